// Round 2
// baseline (400.535 us; speedup 1.0000x reference)
//
#include <hip/hip_runtime.h>

#define FLOOR_EPS 1e-6f

__device__ __forceinline__ float fast_exp2(float x) { return __builtin_amdgcn_exp2f(x); }
__device__ __forceinline__ float fast_log2(float x) { return __builtin_amdgcn_logf(x); }  // v_log_f32 = log2

// One block per (b, c, f) row of length T=4000.
// 256 threads x 16 elements = 4096 coverage; threads with t0 >= T are idle
// for memory but participate in the (zero-padded) scan.
//
// EMA recurrence acc = w*x + q*acc is an affine map with constant A=q, so a
// segment of length L composes to (q^L, partial). Hillis-Steele shuffle scan
// over per-thread segment totals with step multiplier q^(16*s).
__global__ __launch_bounds__(256) void pcen_kernel(
    const float* __restrict__ tf,
    const float* __restrict__ weights,
    const float* __restrict__ alpha,
    const float* __restrict__ delta,
    const float* __restrict__ root,
    float* __restrict__ out,
    int C, int F, int T)
{
    const int row  = blockIdx.x;          // row in [0, B*C*F)
    const int bc   = row / F;             // b*C + c
    const int c    = bc % C;
    const int tid  = threadIdx.x;
    const int lane = tid & 63;
    const int wv   = tid >> 6;

    float w = weights[0];
    w = fminf(fmaxf(w, 0.0f), 1.0f);
    const float q = 1.0f - w;

    const float a    = fminf(alpha[c], 1.0f);
    const float dl   = delta[c];
    const float oor  = 1.0f / fmaxf(root[c], 1.0f);
    const float door = fast_exp2(oor * fast_log2(dl));  // dl^oor (dl=2.0 > 0)

    // tf layout: (B, C, 2F, T). re at (bc*2F + f)*T = (row + bc*F)*T, im += F*T.
    const long long re_off  = (long long)(row + bc * F) * T;
    const long long im_off  = re_off + (long long)F * T;
    const long long out_off = (long long)row * T;

    const int  t0     = tid * 16;
    const bool active = (t0 < T);   // T=4000 -> threads 0..249 active

    // ---- load + magnitude ----
    float m[16];
    if (active) {
        const float4* rp = (const float4*)(tf + re_off + t0);
        const float4* ip = (const float4*)(tf + im_off + t0);
#pragma unroll
        for (int g = 0; g < 4; ++g) {
            float4 r4 = rp[g];
            float4 i4 = ip[g];
            m[4*g+0] = sqrtf(fmaf(r4.x, r4.x, i4.x * i4.x));
            m[4*g+1] = sqrtf(fmaf(r4.y, r4.y, i4.y * i4.y));
            m[4*g+2] = sqrtf(fmaf(r4.z, r4.z, i4.z * i4.z));
            m[4*g+3] = sqrtf(fmaf(r4.w, r4.w, i4.w * i4.w));
        }
    } else {
#pragma unroll
        for (int j = 0; j < 16; ++j) m[j] = 0.0f;
    }

    // ---- per-thread segment total (b-part of the composed affine map) ----
    // Global first element seeds the EMA: b0 = x0 (not w*x0) reproduces
    // ema[0] = x[0] and the (q^t)*x0 tail exactly.
    float p = (t0 == 0) ? m[0] : w * m[0];
#pragma unroll
    for (int j = 1; j < 16; ++j) p = fmaf(q, p, w * m[j]);

    // ---- powers of q ----
    const float q2    = q * q;
    const float q4    = q2 * q2;
    const float q8    = q4 * q4;
    const float q16   = q8 * q8;      // per-thread segment decay
    const float q32   = q16 * q16;
    const float q64   = q32 * q32;
    const float q128  = q64 * q64;
    const float q256  = q128 * q128;
    const float q512  = q256 * q256;
    const float q1024 = q512 * q512;  // per-wave segment decay (64*16 elems)

    // ---- wave-level Hillis-Steele scan over thread segments ----
    float v = p;
    float o;
    o = __shfl_up(v, 1, 64);  if (lane >= 1)  v = fmaf(q16,  o, v);
    o = __shfl_up(v, 2, 64);  if (lane >= 2)  v = fmaf(q32,  o, v);
    o = __shfl_up(v, 4, 64);  if (lane >= 4)  v = fmaf(q64,  o, v);
    o = __shfl_up(v, 8, 64);  if (lane >= 8)  v = fmaf(q128, o, v);
    o = __shfl_up(v, 16, 64); if (lane >= 16) v = fmaf(q256, o, v);
    o = __shfl_up(v, 32, 64); if (lane >= 32) v = fmaf(q512, o, v);

    // ---- cross-wave carry (4 waves) ----
    __shared__ float S[4];
    if (lane == 63) S[wv] = v;
    __syncthreads();

    float carry = 0.0f;  // ema contribution from preceding waves
#pragma unroll
    for (int u = 0; u < 3; ++u)
        carry = (u < wv) ? fmaf(q1024, carry, S[u]) : carry;

    // exclusive within-wave prefix for this thread
    float e = __shfl_up(v, 1, 64);
    if (lane == 0) e = 0.0f;
    // q^(16*lane) via exp2(16*lane*log2(q)); q in (0,1], lane<64 -> exact enough
    const float qlane = fast_exp2((float)(16 * lane) * fast_log2(q));
    const float cin   = fmaf(qlane, carry, e);     // ema state just before t0

    // ---- second pass: reconstruct ema sequentially from cin, emit output ----
    const bool root_is_2 = (oor == 0.5f);  // wave-uniform branch
    float eacc = cin;
    float4* op = (float4*)(out + out_off + t0);
#pragma unroll
    for (int g = 0; g < 4; ++g) {
        float ov[4];
#pragma unroll
        for (int k = 0; k < 4; ++k) {
            const int j  = 4 * g + k;
            float bj = (t0 + j == 0) ? m[0] : w * m[j];
            eacc = fmaf(q, eacc, bj);                       // ema at t0+j
            float ratio = m[j] * fast_exp2(-a * fast_log2(FLOOR_EPS + eacc));
            float s = ratio + dl;
            float r = root_is_2 ? sqrtf(s) : fast_exp2(oor * fast_log2(s));
            ov[k] = r - door;
        }
        if (active) {
            op[g] = make_float4(ov[0], ov[1], ov[2], ov[3]);
        }
    }
}

extern "C" void kernel_launch(void* const* d_in, const int* in_sizes, int n_in,
                              void* d_out, int out_size, void* d_ws, size_t ws_size,
                              hipStream_t stream) {
    const float* tf      = (const float*)d_in[0];
    const float* weights = (const float*)d_in[1];
    const float* alpha   = (const float*)d_in[2];
    const float* delta   = (const float*)d_in[3];
    const float* root    = (const float*)d_in[4];
    float* out = (float*)d_out;

    const int B = 16, C = 2, F = 257, T = 4000;  // FREQ = 2*F = 514
    const int rows = B * C * F;                  // 8224

    pcen_kernel<<<dim3(rows), dim3(256), 0, stream>>>(
        tf, weights, alpha, delta, root, out, C, F, T);
}

// Round 3
// 390.234 us; speedup vs baseline: 1.0264x; 1.0264x over previous
//
#include <hip/hip_runtime.h>

#define FLOOR_EPS 1e-6f

__device__ __forceinline__ float fast_exp2(float x) { return __builtin_amdgcn_exp2f(x); }
__device__ __forceinline__ float fast_log2(float x) { return __builtin_amdgcn_logf(x); }  // v_log_f32 = log2

// One block of 1024 threads per (b, c, f) row of length T=4000.
// Each thread owns 4 contiguous elements => its float4 load/store is
// perfectly coalesced (lane i -> bytes [16i, 16i+16) of the row).
//
// EMA recurrence acc = w*x + q*acc composes over a length-L segment into
// an affine map (q^L, partial). Hillis-Steele shuffle scan over per-thread
// segment partials (decay q^4 per thread), then a 16-wave carry via LDS
// (decay q^256 per wave).
__global__ __launch_bounds__(1024) void pcen_kernel(
    const float* __restrict__ tf,
    const float* __restrict__ weights,
    const float* __restrict__ alpha,
    const float* __restrict__ delta,
    const float* __restrict__ root,
    float* __restrict__ out,
    int C, int F, int T)
{
    const int row  = blockIdx.x;          // row in [0, B*C*F)
    const int bc   = row / F;             // b*C + c
    const int c    = bc % C;
    const int tid  = threadIdx.x;
    const int lane = tid & 63;
    const int wv   = tid >> 6;            // 0..15

    float w = weights[0];
    w = fminf(fmaxf(w, 0.0f), 1.0f);
    const float q = 1.0f - w;

    const float a    = fminf(alpha[c], 1.0f);
    const float dl   = delta[c];
    const float oor  = 1.0f / fmaxf(root[c], 1.0f);
    const float door = fast_exp2(oor * fast_log2(dl));  // dl^oor (dl > 0)

    // tf layout: (B, C, 2F, T). re at (bc*2F + f)*T = (row + bc*F)*T, im += F*T.
    const long long re_off  = (long long)(row + bc * F) * T;
    const long long im_off  = re_off + (long long)F * T;
    const long long out_off = (long long)row * T;

    const int  t0     = tid * 4;
    const bool active = (t0 < T);   // T=4000 -> threads 0..999 active

    // ---- coalesced load + magnitude ----
    float m[4];
    if (active) {
        float4 r4 = *(const float4*)(tf + re_off + t0);
        float4 i4 = *(const float4*)(tf + im_off + t0);
        m[0] = sqrtf(fmaf(r4.x, r4.x, i4.x * i4.x));
        m[1] = sqrtf(fmaf(r4.y, r4.y, i4.y * i4.y));
        m[2] = sqrtf(fmaf(r4.z, r4.z, i4.z * i4.z));
        m[3] = sqrtf(fmaf(r4.w, r4.w, i4.w * i4.w));
    } else {
        m[0] = m[1] = m[2] = m[3] = 0.0f;
    }

    // ---- per-thread segment partial ----
    // Global first element seeds the EMA: b0 = x0 (not w*x0) reproduces
    // ema[0] = x[0] and the (q^t)*x0 tail exactly.
    float p = (t0 == 0) ? m[0] : w * m[0];
#pragma unroll
    for (int j = 1; j < 4; ++j) p = fmaf(q, p, w * m[j]);

    // ---- powers of q ----
    const float q2   = q * q;
    const float q4   = q2 * q2;     // per-thread segment decay
    const float q8   = q4 * q4;
    const float q16  = q8 * q8;
    const float q32  = q16 * q16;
    const float q64  = q32 * q32;
    const float q128 = q64 * q64;
    const float q256 = q128 * q128; // per-wave segment decay (64*4 elems)

    // ---- wave-level Hillis-Steele scan over thread segments ----
    float v = p;
    float o;
    o = __shfl_up(v, 1, 64);  if (lane >= 1)  v = fmaf(q4,   o, v);
    o = __shfl_up(v, 2, 64);  if (lane >= 2)  v = fmaf(q8,   o, v);
    o = __shfl_up(v, 4, 64);  if (lane >= 4)  v = fmaf(q16,  o, v);
    o = __shfl_up(v, 8, 64);  if (lane >= 8)  v = fmaf(q32,  o, v);
    o = __shfl_up(v, 16, 64); if (lane >= 16) v = fmaf(q64,  o, v);
    o = __shfl_up(v, 32, 64); if (lane >= 32) v = fmaf(q128, o, v);

    // ---- cross-wave carry (16 waves) ----
    __shared__ float S[16];
    if (lane == 63) S[wv] = v;
    __syncthreads();

    float carry = 0.0f;  // ema contribution from preceding waves
#pragma unroll
    for (int u = 0; u < 15; ++u)
        carry = (u < wv) ? fmaf(q256, carry, S[u]) : carry;

    // exclusive within-wave prefix for this thread
    float e = __shfl_up(v, 1, 64);
    if (lane == 0) e = 0.0f;
    // q^(4*lane) = exp2(4*lane*log2(q))
    const float qlane = fast_exp2((float)(4 * lane) * fast_log2(q));
    const float cin   = fmaf(qlane, carry, e);   // ema state just before t0

    // ---- reconstruct ema over the 4 elements, emit output ----
    const bool root_is_2 = (oor == 0.5f);  // uniform branch
    float eacc = cin;
    float ov[4];
#pragma unroll
    for (int j = 0; j < 4; ++j) {
        float bj = (t0 + j == 0) ? m[0] : w * m[j];
        eacc = fmaf(q, eacc, bj);                       // ema at t0+j
        float ratio = m[j] * fast_exp2(-a * fast_log2(FLOOR_EPS + eacc));
        float s = ratio + dl;
        float r = root_is_2 ? sqrtf(s) : fast_exp2(oor * fast_log2(s));
        ov[j] = r - door;
    }
    if (active) {
        *(float4*)(out + out_off + t0) = make_float4(ov[0], ov[1], ov[2], ov[3]);
    }
}

extern "C" void kernel_launch(void* const* d_in, const int* in_sizes, int n_in,
                              void* d_out, int out_size, void* d_ws, size_t ws_size,
                              hipStream_t stream) {
    const float* tf      = (const float*)d_in[0];
    const float* weights = (const float*)d_in[1];
    const float* alpha   = (const float*)d_in[2];
    const float* delta   = (const float*)d_in[3];
    const float* root    = (const float*)d_in[4];
    float* out = (float*)d_out;

    const int B = 16, C = 2, F = 257, T = 4000;  // FREQ = 2*F = 514
    const int rows = B * C * F;                  // 8224

    pcen_kernel<<<dim3(rows), dim3(1024), 0, stream>>>(
        tf, weights, alpha, delta, root, out, C, F, T);
}